// Round 3
// baseline (5848.284 us; speedup 1.0000x reference)
//
#include <hip/hip_runtime.h>
#include <hip/hip_bf16.h>
#include <math.h>

#define H 256
#define F 16
#define MUL 16
#define NB 8
#define TILE 16

__device__ __forceinline__ float bf2f(__hip_bfloat16 x) { return __bfloat162float(x); }
__device__ __forceinline__ float silu(float x) { return x / (1.f + __expf(-x)); }

// ---------------- dtype sniffer: is the float data bf16 (flag=0) or fp32 (flag=1)?
// vectors = dirs*r has every component |v| <= 0.95. Read 1024 elements under the
// bf16 interpretation; if any is non-finite or |v| > 1, data must be fp32.
__global__ __launch_bounds__(256) void k_sniff(const void* vec, int* flag)
{
    __shared__ int bad;
    int tid = threadIdx.x;
    if (tid == 0) bad = 0;
    __syncthreads();
    const __hip_bfloat16* hp = (const __hip_bfloat16*)vec;
    for (int i = tid; i < 1024; i += 256) {
        float f = bf2f(hp[i]);
        if (!(isfinite(f) && fabsf(f) <= 1.0f)) bad = 1;
    }
    __syncthreads();
    if (tid == 0) *flag = bad;  // 0 = bf16 mode, 1 = fp32 mode
}

// ---------------- converter: normalize a float input to canonical fp32
__global__ __launch_bounds__(256) void k_conv(const void* src, float* dst, int n,
                                              const int* flag)
{
    int i = blockIdx.x * 256 + threadIdx.x;
    if (i >= n) return;
    if (*flag) dst[i] = ((const float*)src)[i];
    else       dst[i] = bf2f(((const __hip_bfloat16*)src)[i]);
}

// ---------------- Kernel A: per-edge geometry: envelope u, bessel(8), Y(16)
__global__ __launch_bounds__(256) void k_geom(
    const float* __restrict__ vec, float* __restrict__ ubuf,
    float* __restrict__ bess, float* __restrict__ Ybuf, int E)
{
    int e = blockIdx.x * blockDim.x + threadIdx.x;
    if (e >= E) return;
    float vx = vec[3 * e + 0];
    float vy = vec[3 * e + 1];
    float vz = vec[3 * e + 2];
    float d = sqrtf(vx * vx + vy * vy + vz * vz);

    // envelope p=6: u = 1 - 28 d^6 + 48 d^7 - 21 d^8
    float d3 = d * d * d;
    float d6 = d3 * d3, d7 = d6 * d, d8 = d7 * d;
    float u = 1.f - 28.f * d6 + 48.f * d7 - 21.f * d8;
    u = (d < 1.f) ? u : 0.f;
    ubuf[e] = u;

    float invd = 1.f / d;
    const float SQ2 = 1.41421356237309515f;
    const float PI = 3.14159265358979323846f;
#pragma unroll
    for (int k = 1; k <= NB; k++)
        bess[(size_t)e * NB + (k - 1)] = SQ2 * sinf((float)k * PI * d) * invd;

    float x = vx * invd, y = vy * invd, z = vz * invd;
    const float s3 = 1.7320508075688772f;
    const float s5 = 2.2360679774997896f;
    const float s15 = 3.8729833462074170f;
    const float s7 = 2.6457513110645907f;
    const float c33 = 2.0916500663351889f;
    const float c32 = 10.246950765959598f;
    const float c31 = 1.6201851746019651f;
    float* Yp = Ybuf + (size_t)e * 16;
    Yp[0] = 1.f;
    Yp[1] = s3 * x;
    Yp[2] = s3 * y;
    Yp[3] = s3 * z;
    Yp[4] = s15 * x * y;
    Yp[5] = s15 * y * z;
    Yp[6] = 0.5f * s5 * (3.f * z * z - 1.f);
    Yp[7] = s15 * x * z;
    Yp[8] = 0.5f * s15 * (x * x - y * y);
    Yp[9] = c33 * y * (3.f * x * x - y * y);
    Yp[10] = c32 * x * y * z;
    Yp[11] = c31 * y * (5.f * z * z - 1.f);
    Yp[12] = 0.5f * s7 * (5.f * z * z * z - 3.f * z);
    Yp[13] = c31 * x * (5.f * z * z - 1.f);
    Yp[14] = 0.5f * c32 * z * (x * x - y * y);
    Yp[15] = c33 * x * (x * x - 3.f * y * y);
}

// ---------------- Kernel B (fused): x = u*silu(silu(feat@We0+b0)@We1+b1) -> bf16 xbuf
//                                    a = x @ Wv0                          -> abuf
__global__ __launch_bounds__(256) void k_embed(
    const float* __restrict__ bess, const float* __restrict__ na,
    const int* __restrict__ snd, const int* __restrict__ rcv,
    const float* __restrict__ We0, const float* __restrict__ be0,
    const float* __restrict__ We1, const float* __restrict__ be1,
    const float* __restrict__ Wv0, const float* __restrict__ ubuf,
    __hip_bfloat16* __restrict__ xb, float* __restrict__ abuf)
{
    __shared__ float feat[TILE][40];
    __shared__ float xs[TILE][H];
    int e0 = blockIdx.x * TILE;
    int tid = threadIdx.x;
    for (int idx = tid; idx < TILE * 40; idx += 256) {
        int e = idx / 40, c = idx % 40;
        int ge = e0 + e;
        float v;
        if (c < 8) v = bess[(size_t)ge * NB + c];
        else if (c < 24) v = na[(size_t)snd[ge] * F + (c - 8)];
        else v = na[(size_t)rcv[ge] * F + (c - 24)];
        feat[e][c] = v;
    }
    __syncthreads();
    float acc[TILE];
#pragma unroll
    for (int e = 0; e < TILE; e++) acc[e] = 0.f;
    for (int i = 0; i < 40; i++) {
        float wv = We0[i * H + tid];
#pragma unroll
        for (int e = 0; e < TILE; e++) acc[e] += feat[e][i] * wv;
    }
    float bb = be0[tid];
    __syncthreads();
#pragma unroll
    for (int e = 0; e < TILE; e++) xs[e][tid] = silu(acc[e] + bb);
    __syncthreads();
#pragma unroll
    for (int e = 0; e < TILE; e++) acc[e] = 0.f;
    for (int i = 0; i < H; i++) {
        float wv = We1[i * H + tid];
#pragma unroll
        for (int e = 0; e < TILE; e++) acc[e] += xs[e][i] * wv;
    }
    bb = be1[tid];
    float x1[TILE];
#pragma unroll
    for (int e = 0; e < TILE; e++) {
        x1[e] = silu(acc[e] + bb) * ubuf[e0 + e];
        xb[(size_t)(e0 + e) * H + tid] = __float2bfloat16(x1[e]);
    }
    __syncthreads();
#pragma unroll
    for (int e = 0; e < TILE; e++) xs[e][tid] = x1[e];
    __syncthreads();
    int e = tid >> 4, m = tid & 15;
    float a = 0.f;
    for (int i = 0; i < H; i++) a += xs[e][i] * Wv0[i * MUL + m];
    abuf[(size_t)(e0 + e) * MUL + m] = a;
}

// ---------------- Kernel C: w = x @ W_lw[l]; scatter w[m]*Y[i]*inv into wYn[sender]
__global__ __launch_bounds__(256) void k_wscat(
    const __hip_bfloat16* __restrict__ xb, const float* __restrict__ Ybuf,
    const int* __restrict__ snd, const float* __restrict__ Wlw,
    float* __restrict__ wYn)
{
    __shared__ float xs[TILE][H];
    __shared__ float Ys[TILE][16];
    int e0 = blockIdx.x * TILE;
    int tid = threadIdx.x;
    for (int idx = tid; idx < TILE * H; idx += 256)
        xs[idx >> 8][idx & 255] = bf2f(xb[(size_t)e0 * H + idx]);
    Ys[tid >> 4][tid & 15] = Ybuf[(size_t)e0 * 16 + tid];
    __syncthreads();
    int e = tid >> 4, m = tid & 15;
    float w = 0.f;
    for (int i = 0; i < H; i++) w += xs[e][i] * Wlw[i * MUL + m];
    w *= 0.25f;  // inv = 1/sqrt(16)
    int s = snd[e0 + e];
    float* dst = wYn + (size_t)s * 256 + m * 16;
#pragma unroll
    for (int i = 0; i < 16; i++) atomicAdd(&dst[i], w * Ys[e][i]);
}

// ---------------- Kernel D (fused): vv0 + MLP + residual update of x
__global__ __launch_bounds__(256) void k_layer(
    __hip_bfloat16* __restrict__ xb, const float* __restrict__ abuf,
    const float* __restrict__ Ybuf, const float* __restrict__ ubuf,
    const int* __restrict__ snd,
    const float* __restrict__ wYn0, const float* __restrict__ wYn1,
    const float* __restrict__ Wlsh0,
    const float* __restrict__ W1, const float* __restrict__ b1,
    const float* __restrict__ W2, const float* __restrict__ b2,
    int layer)
{
    __shared__ float hs[TILE][272];
    __shared__ float ys[TILE][H];
    __shared__ float Ys[TILE][16];
    __shared__ float us[TILE];
    __shared__ float wl0[16];
    int e0 = blockIdx.x * TILE;
    int tid = threadIdx.x;
    Ys[tid >> 4][tid & 15] = Ybuf[(size_t)e0 * 16 + tid];
    if (tid < TILE) us[tid] = ubuf[e0 + tid];
    if (tid < 16) wl0[tid] = (layer == 1) ? Wlsh0[tid * 16] : 0.f;
    for (int idx = tid; idx < TILE * H; idx += 256)
        hs[idx >> 8][idx & 255] = bf2f(xb[(size_t)e0 * H + idx]);
    __syncthreads();
    {
        int e = tid >> 4, m = tid & 15;
        int s = snd[e0 + e];
        const float* r0 = wYn0 + (size_t)s * 256 + m * 16;
        float a = abuf[(size_t)(e0 + e) * 16 + m];
        float vv;
        if (layer == 0) {
            vv = r0[0] * a;  // Y[e][0] == 1
        } else {
            float t = 0.f;
#pragma unroll
            for (int i = 0; i < 16; i++) t += r0[i] * Ys[e][i] * wl0[i];
            vv = wYn1[(size_t)s * 256 + m * 16] * a * t;
        }
        hs[e][H + m] = vv;
    }
    __syncthreads();
    float acc[TILE];
#pragma unroll
    for (int e = 0; e < TILE; e++) acc[e] = 0.f;
    for (int i = 0; i < 272; i++) {
        float wv = W1[i * H + tid];
#pragma unroll
        for (int e = 0; e < TILE; e++) acc[e] += hs[e][i] * wv;
    }
    float bb = b1[tid];
#pragma unroll
    for (int e = 0; e < TILE; e++) ys[e][tid] = silu(acc[e] + bb);
    __syncthreads();
#pragma unroll
    for (int e = 0; e < TILE; e++) acc[e] = 0.f;
    for (int i = 0; i < H; i++) {
        float wv = W2[i * H + tid];
#pragma unroll
        for (int e = 0; e < TILE; e++) acc[e] += ys[e][i] * wv;
    }
    bb = b2[tid];
    const float rs2 = 0.70710678118654752f;
#pragma unroll
    for (int e = 0; e < TILE; e++) {
        float xn = (hs[e][tid] + us[e] * silu(acc[e] + bb)) * rs2;
        xb[(size_t)(e0 + e) * H + tid] = __float2bfloat16(xn);
    }
}

// ---------------- Kernel E: edge_out = (x @ W_out) * u ; atomic into nacc[receiver]
__global__ __launch_bounds__(256) void k_out(
    const __hip_bfloat16* __restrict__ xb, const float* __restrict__ ubuf,
    const int* __restrict__ rcv, const float* __restrict__ Wout,
    float* __restrict__ nacc)
{
    __shared__ float xs[TILE][H];
    __shared__ float ps[256];
    int e0 = blockIdx.x * TILE;
    int tid = threadIdx.x;
    for (int idx = tid; idx < TILE * H; idx += 256)
        xs[idx >> 8][idx & 255] = bf2f(xb[(size_t)e0 * H + idx]);
    __syncthreads();
    int e = tid >> 4, lane = tid & 15;
    float p = 0.f;
#pragma unroll
    for (int j = 0; j < 16; j++) {
        int i = lane + 16 * j;
        p += xs[e][i] * Wout[i];
    }
    ps[tid] = p;
    __syncthreads();
    if (lane == 0) {
        float s = 0.f;
#pragma unroll
        for (int k = 0; k < 16; k++) s += ps[e * 16 + k];
        atomicAdd(&nacc[rcv[e0 + e]], s * ubuf[e0 + e]);
    }
}

// ---------------- Kernel F: out[n] = nacc[n]*inv in the detected output dtype
__global__ __launch_bounds__(256) void k_final(
    const float* __restrict__ nacc, void* __restrict__ out, const int* __restrict__ flag,
    float inv, int N)
{
    int n = blockIdx.x * 256 + threadIdx.x;
    if (n >= N) return;
    float v = nacc[n] * inv;
    if (*flag) ((float*)out)[n] = v;
    else       ((__hip_bfloat16*)out)[n] = __float2bfloat16(v);
}

extern "C" void kernel_launch(void* const* d_in, const int* in_sizes, int n_in,
                              void* d_out, int out_size, void* d_ws, size_t ws_size,
                              hipStream_t stream)
{
    const int E = in_sizes[2];      // 131072
    const int N = in_sizes[0] / F;  // 8192
    (void)n_in; (void)ws_size; (void)out_size;

    // ---- workspace layout ----
    char* wsb = (char*)d_ws;
    size_t off = 0;
    int* flag = (int*)wsb; off += 256;  // aligned pad

    // canonical fp32 copies of the 14 float inputs (~3.6 MB)
    const int fidx[14] = {0, 1, 4, 5, 6, 7, 8, 9, 10, 11, 12, 13, 14, 15};
    float* canon[14];
    for (int k = 0; k < 14; k++) {
        canon[k] = (float*)(wsb + off);
        off += (size_t)in_sizes[fidx[k]] * 4;
        off = (off + 255) & ~(size_t)255;
    }
    const float* naC   = canon[0];
    const float* vecC  = canon[1];
    const float* We0C  = canon[2];
    const float* be0C  = canon[3];
    const float* We1C  = canon[4];
    const float* be1C  = canon[5];
    const float* Wv0C  = canon[6];
    const float* WlwC  = canon[7];
    const float* WlshC = canon[8];
    const float* Wly1C = canon[9];
    const float* bly1C = canon[10];
    const float* Wly2C = canon[11];
    const float* bly2C = canon[12];
    const float* WoutC = canon[13];

    __hip_bfloat16* xbuf = (__hip_bfloat16*)(wsb + off); off += (size_t)E * H * 2;
    float* ubuf  = (float*)(wsb + off); off += (size_t)E * 4;
    float* bessb = (float*)(wsb + off); off += (size_t)E * NB * 4;
    float* Ybuf  = (float*)(wsb + off); off += (size_t)E * 16 * 4;
    float* abuf  = (float*)(wsb + off); off += (size_t)E * 16 * 4;
    float* wYn0  = (float*)(wsb + off); off += (size_t)N * H * 4;
    float* wYn1  = (float*)(wsb + off); off += (size_t)N * H * 4;
    float* nacc  = (float*)(wsb + off); off += (size_t)N * 4;

    const int* snd = (const int*)d_in[2];
    const int* rcv = (const int*)d_in[3];

    const float inv = 0.25f;
    const int nb = E / TILE;

    // dtype sniff + input normalization
    k_sniff<<<1, 256, 0, stream>>>(d_in[1], flag);
    for (int k = 0; k < 14; k++) {
        int n = in_sizes[fidx[k]];
        k_conv<<<(n + 255) / 256, 256, 0, stream>>>(d_in[fidx[k]], canon[k], n, flag);
    }

    k_geom<<<(E + 255) / 256, 256, 0, stream>>>(vecC, ubuf, bessb, Ybuf, E);
    k_embed<<<nb, 256, 0, stream>>>(bessb, naC, snd, rcv, We0C, be0C, We1C, be1C,
                                    Wv0C, ubuf, xbuf, abuf);

    // layer 0
    hipMemsetAsync(wYn0, 0, (size_t)N * H * sizeof(float), stream);
    k_wscat<<<nb, 256, 0, stream>>>(xbuf, Ybuf, snd, WlwC, wYn0);
    k_layer<<<nb, 256, 0, stream>>>(xbuf, abuf, Ybuf, ubuf, snd, wYn0, wYn0, WlshC,
                                    Wly1C, bly1C, Wly2C, bly2C, 0);
    // layer 1
    hipMemsetAsync(wYn1, 0, (size_t)N * H * sizeof(float), stream);
    k_wscat<<<nb, 256, 0, stream>>>(xbuf, Ybuf, snd, WlwC + (size_t)H * MUL, wYn1);
    k_layer<<<nb, 256, 0, stream>>>(xbuf, abuf, Ybuf, ubuf, snd, wYn0, wYn1, WlshC,
                                    Wly1C + (size_t)272 * H, bly1C + H,
                                    Wly2C + (size_t)H * H, bly2C + H, 1);

    hipMemsetAsync(nacc, 0, (size_t)N * sizeof(float), stream);
    k_out<<<nb, 256, 0, stream>>>(xbuf, ubuf, rcv, WoutC, nacc);
    k_final<<<(N + 255) / 256, 256, 0, stream>>>(nacc, d_out, flag, inv, N);
}

// Round 4
// 2054.435 us; speedup vs baseline: 2.8467x; 2.8467x over previous
//
#include <hip/hip_runtime.h>
#include <hip/hip_bf16.h>
#include <math.h>

#define H 256
#define F 16
#define MUL 16
#define NB 8
#define TILE 16

__device__ __forceinline__ float bf2f(__hip_bfloat16 x) { return __bfloat162float(x); }
__device__ __forceinline__ float silu(float x) { return x / (1.f + __expf(-x)); }

// ---------------- dtype sniffer: is the float data bf16 (flag=0) or fp32 (flag=1)?
__global__ __launch_bounds__(256) void k_sniff(const void* vec, int* flag)
{
    __shared__ int bad;
    int tid = threadIdx.x;
    if (tid == 0) bad = 0;
    __syncthreads();
    const __hip_bfloat16* hp = (const __hip_bfloat16*)vec;
    for (int i = tid; i < 1024; i += 256) {
        float f = bf2f(hp[i]);
        if (!(isfinite(f) && fabsf(f) <= 1.0f)) bad = 1;
    }
    __syncthreads();
    if (tid == 0) *flag = bad;
}

// ---------------- converter: normalize a float input to canonical fp32
__global__ __launch_bounds__(256) void k_conv(const void* src, float* dst, int n,
                                              const int* flag)
{
    int i = blockIdx.x * 256 + threadIdx.x;
    if (i >= n) return;
    if (*flag) dst[i] = ((const float*)src)[i];
    else       dst[i] = bf2f(((const __hip_bfloat16*)src)[i]);
}

// ---------------- CSR build: histogram of senders
__global__ __launch_bounds__(256) void k_hist(const int* __restrict__ snd,
                                              int* __restrict__ cnt, int E)
{
    int e = blockIdx.x * 256 + threadIdx.x;
    if (e < E) atomicAdd(&cnt[snd[e]], 1);
}

// ---------------- CSR build: single-block exclusive scan (N <= 256*chunk)
__global__ __launch_bounds__(256) void k_scan(const int* __restrict__ cnt,
                                              int* __restrict__ off,
                                              int* __restrict__ cur, int N)
{
    __shared__ int sums[256];
    int tid = threadIdx.x;
    int chunk = (N + 255) / 256;
    int base = tid * chunk;
    int s = 0;
    for (int i = 0; i < chunk; i++) {
        int idx = base + i;
        if (idx < N) s += cnt[idx];
    }
    sums[tid] = s;
    __syncthreads();
    for (int d = 1; d < 256; d <<= 1) {
        int v = (tid >= d) ? sums[tid - d] : 0;
        __syncthreads();
        sums[tid] += v;
        __syncthreads();
    }
    int run = (tid == 0) ? 0 : sums[tid - 1];
    for (int i = 0; i < chunk; i++) {
        int idx = base + i;
        if (idx < N) { off[idx] = run; cur[idx] = run; run += cnt[idx]; }
    }
    if (tid == 255) off[N] = run;
}

// ---------------- CSR build: scatter edge ids into rows
__global__ __launch_bounds__(256) void k_cscatter(const int* __restrict__ snd,
                                                  int* __restrict__ cur,
                                                  int* __restrict__ eidx, int E)
{
    int e = blockIdx.x * 256 + threadIdx.x;
    if (e >= E) return;
    int p = atomicAdd(&cur[snd[e]], 1);
    eidx[p] = e;
}

// ---------------- Kernel A: per-edge geometry: envelope u, bessel(8), Y(16)
__global__ __launch_bounds__(256) void k_geom(
    const float* __restrict__ vec, float* __restrict__ ubuf,
    float* __restrict__ bess, float* __restrict__ Ybuf, int E)
{
    int e = blockIdx.x * blockDim.x + threadIdx.x;
    if (e >= E) return;
    float vx = vec[3 * e + 0];
    float vy = vec[3 * e + 1];
    float vz = vec[3 * e + 2];
    float d = sqrtf(vx * vx + vy * vy + vz * vz);

    float d3 = d * d * d;
    float d6 = d3 * d3, d7 = d6 * d, d8 = d7 * d;
    float u = 1.f - 28.f * d6 + 48.f * d7 - 21.f * d8;
    u = (d < 1.f) ? u : 0.f;
    ubuf[e] = u;

    float invd = 1.f / d;
    const float SQ2 = 1.41421356237309515f;
    const float PI = 3.14159265358979323846f;
#pragma unroll
    for (int k = 1; k <= NB; k++)
        bess[(size_t)e * NB + (k - 1)] = SQ2 * sinf((float)k * PI * d) * invd;

    float x = vx * invd, y = vy * invd, z = vz * invd;
    const float s3 = 1.7320508075688772f;
    const float s5 = 2.2360679774997896f;
    const float s15 = 3.8729833462074170f;
    const float s7 = 2.6457513110645907f;
    const float c33 = 2.0916500663351889f;
    const float c32 = 10.246950765959598f;
    const float c31 = 1.6201851746019651f;
    float* Yp = Ybuf + (size_t)e * 16;
    Yp[0] = 1.f;
    Yp[1] = s3 * x;
    Yp[2] = s3 * y;
    Yp[3] = s3 * z;
    Yp[4] = s15 * x * y;
    Yp[5] = s15 * y * z;
    Yp[6] = 0.5f * s5 * (3.f * z * z - 1.f);
    Yp[7] = s15 * x * z;
    Yp[8] = 0.5f * s15 * (x * x - y * y);
    Yp[9] = c33 * y * (3.f * x * x - y * y);
    Yp[10] = c32 * x * y * z;
    Yp[11] = c31 * y * (5.f * z * z - 1.f);
    Yp[12] = 0.5f * s7 * (5.f * z * z * z - 3.f * z);
    Yp[13] = c31 * x * (5.f * z * z - 1.f);
    Yp[14] = 0.5f * c32 * z * (x * x - y * y);
    Yp[15] = c33 * x * (x * x - 3.f * y * y);
}

// ---------------- Kernel B (fused): x = u*silu(silu(feat@We0+b0)@We1+b1) -> bf16 xbuf
//                                    a = x @ Wv0                          -> abuf
__global__ __launch_bounds__(256) void k_embed(
    const float* __restrict__ bess, const float* __restrict__ na,
    const int* __restrict__ snd, const int* __restrict__ rcv,
    const float* __restrict__ We0, const float* __restrict__ be0,
    const float* __restrict__ We1, const float* __restrict__ be1,
    const float* __restrict__ Wv0, const float* __restrict__ ubuf,
    __hip_bfloat16* __restrict__ xb, float* __restrict__ abuf)
{
    __shared__ float feat[TILE][40];
    __shared__ float xs[TILE][H];
    int e0 = blockIdx.x * TILE;
    int tid = threadIdx.x;
    for (int idx = tid; idx < TILE * 40; idx += 256) {
        int e = idx / 40, c = idx % 40;
        int ge = e0 + e;
        float v;
        if (c < 8) v = bess[(size_t)ge * NB + c];
        else if (c < 24) v = na[(size_t)snd[ge] * F + (c - 8)];
        else v = na[(size_t)rcv[ge] * F + (c - 24)];
        feat[e][c] = v;
    }
    __syncthreads();
    float acc[TILE];
#pragma unroll
    for (int e = 0; e < TILE; e++) acc[e] = 0.f;
    for (int i = 0; i < 40; i++) {
        float wv = We0[i * H + tid];
#pragma unroll
        for (int e = 0; e < TILE; e++) acc[e] += feat[e][i] * wv;
    }
    float bb = be0[tid];
    __syncthreads();
#pragma unroll
    for (int e = 0; e < TILE; e++) xs[e][tid] = silu(acc[e] + bb);
    __syncthreads();
#pragma unroll
    for (int e = 0; e < TILE; e++) acc[e] = 0.f;
    for (int i = 0; i < H; i++) {
        float wv = We1[i * H + tid];
#pragma unroll
        for (int e = 0; e < TILE; e++) acc[e] += xs[e][i] * wv;
    }
    bb = be1[tid];
    float x1[TILE];
#pragma unroll
    for (int e = 0; e < TILE; e++) {
        x1[e] = silu(acc[e] + bb) * ubuf[e0 + e];
        xb[(size_t)(e0 + e) * H + tid] = __float2bfloat16(x1[e]);
    }
    __syncthreads();
#pragma unroll
    for (int e = 0; e < TILE; e++) xs[e][tid] = x1[e];
    __syncthreads();
    int e = tid >> 4, m = tid & 15;
    float a = 0.f;
    for (int i = 0; i < H; i++) a += xs[e][i] * Wv0[i * MUL + m];
    abuf[(size_t)(e0 + e) * MUL + m] = a;
}

// ---------------- Kernel C1: w = x @ W_lw[l] -> wbuf (E x 16), no atomics
__global__ __launch_bounds__(256) void k_wcomp(
    const __hip_bfloat16* __restrict__ xb, const float* __restrict__ Wlw,
    float* __restrict__ wbuf)
{
    __shared__ float xs[TILE][H];
    int e0 = blockIdx.x * TILE;
    int tid = threadIdx.x;
    for (int idx = tid; idx < TILE * H; idx += 256)
        xs[idx >> 8][idx & 255] = bf2f(xb[(size_t)e0 * H + idx]);
    __syncthreads();
    int e = tid >> 4, m = tid & 15;
    float w = 0.f;
    for (int i = 0; i < H; i++) w += xs[e][i] * Wlw[i * MUL + m];
    wbuf[(size_t)(e0 + e) * 16 + m] = w;
}

// ---------------- Kernel C2: CSR gather: wYn[n,m,i] = inv * sum_e w[e,m]*Y[e,i]
__global__ __launch_bounds__(256) void k_gather(
    const int* __restrict__ off, const int* __restrict__ eidx,
    const float* __restrict__ wbuf, const float* __restrict__ Ybuf,
    float* __restrict__ wYn)
{
    __shared__ float ws[16][16];
    __shared__ float Ysh[16][16];
    int n = blockIdx.x;
    int tid = threadIdx.x;
    int m = tid >> 4, i = tid & 15;
    int beg = off[n], end = off[n + 1];
    float acc = 0.f;
    for (int c = beg; c < end; c += 16) {
        int ne = min(16, end - c);
        int j = tid >> 4, k = tid & 15;
        if (j < ne) {
            int e = eidx[c + j];
            ws[j][k] = wbuf[(size_t)e * 16 + k];
            Ysh[j][k] = Ybuf[(size_t)e * 16 + k];
        }
        __syncthreads();
        for (int j2 = 0; j2 < ne; j2++) acc += ws[j2][m] * Ysh[j2][i];
        __syncthreads();
    }
    wYn[(size_t)n * 256 + m * 16 + i] = acc * 0.25f;  // inv = 1/sqrt(16)
}

// ---------------- Kernel D (fused): vv0 + MLP + residual update of x
__global__ __launch_bounds__(256) void k_layer(
    __hip_bfloat16* __restrict__ xb, const float* __restrict__ abuf,
    const float* __restrict__ Ybuf, const float* __restrict__ ubuf,
    const int* __restrict__ snd,
    const float* __restrict__ wYn0, const float* __restrict__ wYn1,
    const float* __restrict__ Wlsh0,
    const float* __restrict__ W1, const float* __restrict__ b1,
    const float* __restrict__ W2, const float* __restrict__ b2,
    int layer)
{
    __shared__ float hs[TILE][272];
    __shared__ float ys[TILE][H];
    __shared__ float Ys[TILE][16];
    __shared__ float us[TILE];
    __shared__ float wl0[16];
    int e0 = blockIdx.x * TILE;
    int tid = threadIdx.x;
    Ys[tid >> 4][tid & 15] = Ybuf[(size_t)e0 * 16 + tid];
    if (tid < TILE) us[tid] = ubuf[e0 + tid];
    if (tid < 16) wl0[tid] = (layer == 1) ? Wlsh0[tid * 16] : 0.f;
    for (int idx = tid; idx < TILE * H; idx += 256)
        hs[idx >> 8][idx & 255] = bf2f(xb[(size_t)e0 * H + idx]);
    __syncthreads();
    {
        int e = tid >> 4, m = tid & 15;
        int s = snd[e0 + e];
        const float* r0 = wYn0 + (size_t)s * 256 + m * 16;
        float a = abuf[(size_t)(e0 + e) * 16 + m];
        float vv;
        if (layer == 0) {
            vv = r0[0] * a;  // Y[e][0] == 1
        } else {
            float t = 0.f;
#pragma unroll
            for (int i = 0; i < 16; i++) t += r0[i] * Ys[e][i] * wl0[i];
            vv = wYn1[(size_t)s * 256 + m * 16] * a * t;
        }
        hs[e][H + m] = vv;
    }
    __syncthreads();
    float acc[TILE];
#pragma unroll
    for (int e = 0; e < TILE; e++) acc[e] = 0.f;
    for (int i = 0; i < 272; i++) {
        float wv = W1[i * H + tid];
#pragma unroll
        for (int e = 0; e < TILE; e++) acc[e] += hs[e][i] * wv;
    }
    float bb = b1[tid];
#pragma unroll
    for (int e = 0; e < TILE; e++) ys[e][tid] = silu(acc[e] + bb);
    __syncthreads();
#pragma unroll
    for (int e = 0; e < TILE; e++) acc[e] = 0.f;
    for (int i = 0; i < H; i++) {
        float wv = W2[i * H + tid];
#pragma unroll
        for (int e = 0; e < TILE; e++) acc[e] += ys[e][i] * wv;
    }
    bb = b2[tid];
    const float rs2 = 0.70710678118654752f;
#pragma unroll
    for (int e = 0; e < TILE; e++) {
        float xn = (hs[e][tid] + us[e] * silu(acc[e] + bb)) * rs2;
        xb[(size_t)(e0 + e) * H + tid] = __float2bfloat16(xn);
    }
}

// ---------------- Kernel E: edge_out = (x @ W_out) * u ; atomic into nacc[receiver]
__global__ __launch_bounds__(256) void k_out(
    const __hip_bfloat16* __restrict__ xb, const float* __restrict__ ubuf,
    const int* __restrict__ rcv, const float* __restrict__ Wout,
    float* __restrict__ nacc)
{
    __shared__ float xs[TILE][H];
    __shared__ float ps[256];
    int e0 = blockIdx.x * TILE;
    int tid = threadIdx.x;
    for (int idx = tid; idx < TILE * H; idx += 256)
        xs[idx >> 8][idx & 255] = bf2f(xb[(size_t)e0 * H + idx]);
    __syncthreads();
    int e = tid >> 4, lane = tid & 15;
    float p = 0.f;
#pragma unroll
    for (int j = 0; j < 16; j++) {
        int i = lane + 16 * j;
        p += xs[e][i] * Wout[i];
    }
    ps[tid] = p;
    __syncthreads();
    if (lane == 0) {
        float s = 0.f;
#pragma unroll
        for (int k = 0; k < 16; k++) s += ps[e * 16 + k];
        atomicAdd(&nacc[rcv[e0 + e]], s * ubuf[e0 + e]);
    }
}

// ---------------- Kernel F: out[n] = nacc[n]*inv in the detected output dtype
__global__ __launch_bounds__(256) void k_final(
    const float* __restrict__ nacc, void* __restrict__ out, const int* __restrict__ flag,
    float inv, int N)
{
    int n = blockIdx.x * 256 + threadIdx.x;
    if (n >= N) return;
    float v = nacc[n] * inv;
    if (*flag) ((float*)out)[n] = v;
    else       ((__hip_bfloat16*)out)[n] = __float2bfloat16(v);
}

extern "C" void kernel_launch(void* const* d_in, const int* in_sizes, int n_in,
                              void* d_out, int out_size, void* d_ws, size_t ws_size,
                              hipStream_t stream)
{
    const int E = in_sizes[2];      // 131072
    const int N = in_sizes[0] / F;  // 8192
    (void)n_in; (void)ws_size; (void)out_size;

    // ---- workspace layout (~112 MB) ----
    char* wsb = (char*)d_ws;
    size_t off = 0;
    int* flag = (int*)wsb; off += 256;

    const int fidx[14] = {0, 1, 4, 5, 6, 7, 8, 9, 10, 11, 12, 13, 14, 15};
    float* canon[14];
    for (int k = 0; k < 14; k++) {
        canon[k] = (float*)(wsb + off);
        off += (size_t)in_sizes[fidx[k]] * 4;
        off = (off + 255) & ~(size_t)255;
    }
    const float* naC   = canon[0];
    const float* vecC  = canon[1];
    const float* We0C  = canon[2];
    const float* be0C  = canon[3];
    const float* We1C  = canon[4];
    const float* be1C  = canon[5];
    const float* Wv0C  = canon[6];
    const float* WlwC  = canon[7];
    const float* WlshC = canon[8];
    const float* Wly1C = canon[9];
    const float* bly1C = canon[10];
    const float* Wly2C = canon[11];
    const float* bly2C = canon[12];
    const float* WoutC = canon[13];

    __hip_bfloat16* xbuf = (__hip_bfloat16*)(wsb + off); off += (size_t)E * H * 2;
    // bessb (E*8 f32) and wbuf (E*16 f32) share one 8 MB region:
    // bessb dies after k_embed; wbuf is written only after that.
    float* bessb = (float*)(wsb + off);
    float* wbuf  = (float*)(wsb + off); off += (size_t)E * 16 * 4;
    float* ubuf  = (float*)(wsb + off); off += (size_t)E * 4;
    float* Ybuf  = (float*)(wsb + off); off += (size_t)E * 16 * 4;
    float* abuf  = (float*)(wsb + off); off += (size_t)E * 16 * 4;
    float* wYn0  = (float*)(wsb + off); off += (size_t)N * H * 4;
    float* wYn1  = (float*)(wsb + off); off += (size_t)N * H * 4;
    float* nacc  = (float*)(wsb + off); off += (size_t)N * 4;
    int* cnt  = (int*)(wsb + off); off += (size_t)N * 4;
    int* offb = (int*)(wsb + off); off += (size_t)(N + 1) * 4;
    int* cur  = (int*)(wsb + off); off += (size_t)N * 4;
    int* eidx = (int*)(wsb + off); off += (size_t)E * 4;

    const int* snd = (const int*)d_in[2];
    const int* rcv = (const int*)d_in[3];

    const float inv = 0.25f;
    const int nb = E / TILE;

    // dtype sniff + input normalization
    k_sniff<<<1, 256, 0, stream>>>(d_in[1], flag);
    for (int k = 0; k < 14; k++) {
        int n = in_sizes[fidx[k]];
        k_conv<<<(n + 255) / 256, 256, 0, stream>>>(d_in[fidx[k]], canon[k], n, flag);
    }

    // sender CSR
    hipMemsetAsync(cnt, 0, (size_t)N * sizeof(int), stream);
    k_hist<<<(E + 255) / 256, 256, 0, stream>>>(snd, cnt, E);
    k_scan<<<1, 256, 0, stream>>>(cnt, offb, cur, N);
    k_cscatter<<<(E + 255) / 256, 256, 0, stream>>>(snd, cur, eidx, E);

    k_geom<<<(E + 255) / 256, 256, 0, stream>>>(vecC, ubuf, bessb, Ybuf, E);
    k_embed<<<nb, 256, 0, stream>>>(bessb, naC, snd, rcv, We0C, be0C, We1C, be1C,
                                    Wv0C, ubuf, xbuf, abuf);

    // layer 0
    k_wcomp<<<nb, 256, 0, stream>>>(xbuf, WlwC, wbuf);
    k_gather<<<N, 256, 0, stream>>>(offb, eidx, wbuf, Ybuf, wYn0);
    k_layer<<<nb, 256, 0, stream>>>(xbuf, abuf, Ybuf, ubuf, snd, wYn0, wYn0, WlshC,
                                    Wly1C, bly1C, Wly2C, bly2C, 0);
    // layer 1
    k_wcomp<<<nb, 256, 0, stream>>>(xbuf, WlwC + (size_t)H * MUL, wbuf);
    k_gather<<<N, 256, 0, stream>>>(offb, eidx, wbuf, Ybuf, wYn1);
    k_layer<<<nb, 256, 0, stream>>>(xbuf, abuf, Ybuf, ubuf, snd, wYn0, wYn1, WlshC,
                                    Wly1C + (size_t)272 * H, bly1C + H,
                                    Wly2C + (size_t)H * H, bly2C + H, 1);

    hipMemsetAsync(nacc, 0, (size_t)N * sizeof(float), stream);
    k_out<<<nb, 256, 0, stream>>>(xbuf, ubuf, rcv, WoutC, nacc);
    k_final<<<(N + 255) / 256, 256, 0, stream>>>(nacc, d_out, flag, inv, N);
}

// Round 5
// 845.228 us; speedup vs baseline: 6.9192x; 2.4306x over previous
//
#include <hip/hip_runtime.h>
#include <hip/hip_bf16.h>
#include <math.h>

#define H 256
#define F 16
#define MUL 16
#define NB 8

typedef short bf16x8 __attribute__((ext_vector_type(8)));
typedef float f32x4 __attribute__((ext_vector_type(4)));
#define MFMA_B16(a, b, c) __builtin_amdgcn_mfma_f32_16x16x32_bf16(a, b, c, 0, 0, 0)

__device__ __forceinline__ float bf2f(__hip_bfloat16 x) { return __bfloat162float(x); }
__device__ __forceinline__ float silu(float x) { return x / (1.f + __expf(-x)); }

// ---------------- dtype sniffer: bf16 (flag=0) or fp32 (flag=1)?
__global__ __launch_bounds__(256) void k_sniff(const void* vec, int* flag)
{
    __shared__ int bad;
    int tid = threadIdx.x;
    if (tid == 0) bad = 0;
    __syncthreads();
    const __hip_bfloat16* hp = (const __hip_bfloat16*)vec;
    for (int i = tid; i < 1024; i += 256) {
        float f = bf2f(hp[i]);
        if (!(isfinite(f) && fabsf(f) <= 1.0f)) bad = 1;
    }
    __syncthreads();
    if (tid == 0) *flag = bad;
}

__global__ __launch_bounds__(256) void k_conv(const void* src, float* dst, int n,
                                              const int* flag)
{
    int i = blockIdx.x * 256 + threadIdx.x;
    if (i >= n) return;
    if (*flag) dst[i] = ((const float*)src)[i];
    else       dst[i] = bf2f(((const __hip_bfloat16*)src)[i]);
}

// ---------------- weight swizzle: fp32 row-major [K][N] -> bf16 frag-linear
// out[(kt*N + n)*32 + kk] = W[(kt*32+kk)][n], zero-padded to Kpad
__global__ __launch_bounds__(256) void k_swz(const float* __restrict__ W,
                                             __hip_bfloat16* __restrict__ out,
                                             int K, int Ncols, int Kpad)
{
    int idx = blockIdx.x * 256 + threadIdx.x;
    int total = (Kpad >> 5) * Ncols * 32;
    if (idx >= total) return;
    int kk = idx & 31;
    int n = (idx >> 5) % Ncols;
    int kt = idx / (32 * Ncols);
    int k = kt * 32 + kk;
    float v = (k < K) ? W[(size_t)k * Ncols + n] : 0.f;
    out[idx] = __float2bfloat16(v);
}

// ---------------- CSR build
__global__ __launch_bounds__(256) void k_hist(const int* __restrict__ snd,
                                              int* __restrict__ cnt, int E)
{
    int e = blockIdx.x * 256 + threadIdx.x;
    if (e < E) atomicAdd(&cnt[snd[e]], 1);
}

__global__ __launch_bounds__(256) void k_scan(const int* __restrict__ cnt,
                                              int* __restrict__ off,
                                              int* __restrict__ cur, int N)
{
    __shared__ int sums[256];
    int tid = threadIdx.x;
    int chunk = (N + 255) / 256;
    int base = tid * chunk;
    int s = 0;
    for (int i = 0; i < chunk; i++) { int idx = base + i; if (idx < N) s += cnt[idx]; }
    sums[tid] = s;
    __syncthreads();
    for (int d = 1; d < 256; d <<= 1) {
        int v = (tid >= d) ? sums[tid - d] : 0;
        __syncthreads();
        sums[tid] += v;
        __syncthreads();
    }
    int run = (tid == 0) ? 0 : sums[tid - 1];
    for (int i = 0; i < chunk; i++) {
        int idx = base + i;
        if (idx < N) { off[idx] = run; cur[idx] = run; run += cnt[idx]; }
    }
    if (tid == 255) off[N] = run;
}

__global__ __launch_bounds__(256) void k_cscatter(const int* __restrict__ snd,
                                                  int* __restrict__ cur,
                                                  int* __restrict__ eidx, int E)
{
    int e = blockIdx.x * 256 + threadIdx.x;
    if (e >= E) return;
    int p = atomicAdd(&cur[snd[e]], 1);
    eidx[p] = e;
}

// ---------------- geometry: u, Y(16) fp32; fbuf[E][64] bf16 = [bessel8|na_s16|na_r16|0]
__global__ __launch_bounds__(256) void k_geom(
    const float* __restrict__ vec, const float* __restrict__ na,
    const int* __restrict__ snd, const int* __restrict__ rcv,
    float* __restrict__ ubuf, float* __restrict__ Ybuf,
    __hip_bfloat16* __restrict__ fbuf, int E)
{
    int e = blockIdx.x * blockDim.x + threadIdx.x;
    if (e >= E) return;
    float vx = vec[3 * e + 0], vy = vec[3 * e + 1], vz = vec[3 * e + 2];
    float d = sqrtf(vx * vx + vy * vy + vz * vz);

    float d3 = d * d * d;
    float d6 = d3 * d3, d7 = d6 * d, d8 = d7 * d;
    float u = 1.f - 28.f * d6 + 48.f * d7 - 21.f * d8;
    u = (d < 1.f) ? u : 0.f;
    ubuf[e] = u;

    float invd = 1.f / d;
    const float SQ2 = 1.41421356237309515f;
    const float PI = 3.14159265358979323846f;
    __hip_bfloat16* fp = fbuf + (size_t)e * 64;
#pragma unroll
    for (int k = 1; k <= NB; k++)
        fp[k - 1] = __float2bfloat16(SQ2 * sinf((float)k * PI * d) * invd);
    int s = snd[e], r = rcv[e];
#pragma unroll
    for (int j = 0; j < 16; j++) fp[8 + j] = __float2bfloat16(na[(size_t)s * F + j]);
#pragma unroll
    for (int j = 0; j < 16; j++) fp[24 + j] = __float2bfloat16(na[(size_t)r * F + j]);
#pragma unroll
    for (int j = 40; j < 64; j++) fp[j] = __float2bfloat16(0.f);

    float x = vx * invd, y = vy * invd, z = vz * invd;
    const float s3 = 1.7320508075688772f;
    const float s5 = 2.2360679774997896f;
    const float s15 = 3.8729833462074170f;
    const float s7 = 2.6457513110645907f;
    const float c33 = 2.0916500663351889f;
    const float c32 = 10.246950765959598f;
    const float c31 = 1.6201851746019651f;
    float* Yp = Ybuf + (size_t)e * 16;
    Yp[0] = 1.f;
    Yp[1] = s3 * x;  Yp[2] = s3 * y;  Yp[3] = s3 * z;
    Yp[4] = s15 * x * y;  Yp[5] = s15 * y * z;
    Yp[6] = 0.5f * s5 * (3.f * z * z - 1.f);
    Yp[7] = s15 * x * z;
    Yp[8] = 0.5f * s15 * (x * x - y * y);
    Yp[9] = c33 * y * (3.f * x * x - y * y);
    Yp[10] = c32 * x * y * z;
    Yp[11] = c31 * y * (5.f * z * z - 1.f);
    Yp[12] = 0.5f * s7 * (5.f * z * z * z - 3.f * z);
    Yp[13] = c31 * x * (5.f * z * z - 1.f);
    Yp[14] = 0.5f * c32 * z * (x * x - y * y);
    Yp[15] = c33 * x * (x * x - 3.f * y * y);
}

// ---------------- MFMA embed: x = u*silu(silu(feat@We0+b0)@We1+b1) -> xb (bf16)
//                              a = x @ Wv0 -> abuf (fp32)
// block = 64 edges, 4 waves; wave owns 16 edges.
__global__ __launch_bounds__(256) void k_embed_mfma(
    const __hip_bfloat16* __restrict__ fbuf,
    const __hip_bfloat16* __restrict__ We0s, const float* __restrict__ be0,
    const __hip_bfloat16* __restrict__ We1s, const float* __restrict__ be1,
    const __hip_bfloat16* __restrict__ Wv0s, const float* __restrict__ ubuf,
    __hip_bfloat16* __restrict__ xb, float* __restrict__ abuf)
{
    __shared__ __hip_bfloat16 ys[4][16 * 264];  // row pad +8 -> 2-way bank conflicts only
    int tid = threadIdx.x;
    int w = tid >> 6, l = tid & 63;
    int lm = l & 15, lq = l >> 4;
    int erow = blockIdx.x * 64 + w * 16;
    __hip_bfloat16* Y = &ys[w][0];

    // GEMM1: [16x64] @ [64x256]
    f32x4 acc[16];
#pragma unroll
    for (int nt = 0; nt < 16; nt++) acc[nt] = (f32x4){0.f, 0.f, 0.f, 0.f};
#pragma unroll
    for (int kt = 0; kt < 2; kt++) {
        bf16x8 a = *(const bf16x8*)(fbuf + (size_t)(erow + lm) * 64 + kt * 32 + lq * 8);
#pragma unroll
        for (int nt = 0; nt < 16; nt++) {
            bf16x8 b = *(const bf16x8*)(We0s + ((size_t)(kt * 256 + nt * 16 + lm) * 32 + lq * 8));
            acc[nt] = MFMA_B16(a, b, acc[nt]);
        }
    }
#pragma unroll
    for (int nt = 0; nt < 16; nt++) {
        int c = nt * 16 + lm;
        float bb = be0[c];
#pragma unroll
        for (int r = 0; r < 4; r++)
            Y[(lq * 4 + r) * 264 + c] = __float2bfloat16(silu(acc[nt][r] + bb));
    }
    __syncthreads();

    // GEMM2: [16x256] @ [256x256]
#pragma unroll
    for (int nt = 0; nt < 16; nt++) acc[nt] = (f32x4){0.f, 0.f, 0.f, 0.f};
#pragma unroll
    for (int kt = 0; kt < 8; kt++) {
        bf16x8 a = *(const bf16x8*)(Y + lm * 264 + kt * 32 + lq * 8);
#pragma unroll
        for (int nt = 0; nt < 16; nt++) {
            bf16x8 b = *(const bf16x8*)(We1s + ((size_t)(kt * 256 + nt * 16 + lm) * 32 + lq * 8));
            acc[nt] = MFMA_B16(a, b, acc[nt]);
        }
    }
    __syncthreads();
    float uu[4];
#pragma unroll
    for (int r = 0; r < 4; r++) uu[r] = ubuf[erow + lq * 4 + r];
#pragma unroll
    for (int nt = 0; nt < 16; nt++) {
        int c = nt * 16 + lm;
        float bb = be1[c];
#pragma unroll
        for (int r = 0; r < 4; r++) {
            float v = silu(acc[nt][r] + bb) * uu[r];
            __hip_bfloat16 hv = __float2bfloat16(v);
            xb[(size_t)(erow + lq * 4 + r) * H + c] = hv;
            Y[(lq * 4 + r) * 264 + c] = hv;
        }
    }
    __syncthreads();

    // GEMM3: a = x @ Wv0  [16x256]@[256x16]
    f32x4 acc3 = (f32x4){0.f, 0.f, 0.f, 0.f};
#pragma unroll
    for (int kt = 0; kt < 8; kt++) {
        bf16x8 a = *(const bf16x8*)(Y + lm * 264 + kt * 32 + lq * 8);
        bf16x8 b = *(const bf16x8*)(Wv0s + ((size_t)(kt * 16 + lm) * 32 + lq * 8));
        acc3 = MFMA_B16(a, b, acc3);
    }
#pragma unroll
    for (int r = 0; r < 4; r++)
        abuf[(size_t)(erow + lq * 4 + r) * 16 + lm] = acc3[r];
}

// ---------------- MFMA wcomp: w = x @ Wlw[l]  -> wbuf (E x 16 fp32)
__global__ __launch_bounds__(256) void k_wcomp_mfma(
    const __hip_bfloat16* __restrict__ xb, const __hip_bfloat16* __restrict__ Wlws,
    float* __restrict__ wbuf)
{
    int tid = threadIdx.x;
    int w = tid >> 6, l = tid & 63;
    int lm = l & 15, lq = l >> 4;
    int erow = blockIdx.x * 64 + w * 16;
    f32x4 acc = (f32x4){0.f, 0.f, 0.f, 0.f};
#pragma unroll
    for (int kt = 0; kt < 8; kt++) {
        bf16x8 a = *(const bf16x8*)(xb + (size_t)(erow + lm) * H + kt * 32 + lq * 8);
        bf16x8 b = *(const bf16x8*)(Wlws + ((size_t)(kt * 16 + lm) * 32 + lq * 8));
        acc = MFMA_B16(a, b, acc);
    }
#pragma unroll
    for (int r = 0; r < 4; r++)
        wbuf[(size_t)(erow + lq * 4 + r) * 16 + lm] = acc[r];
}

// ---------------- CSR gather: wYn[n,m,i] = inv * sum_e w[e,m]*Y[e,i]
__global__ __launch_bounds__(256) void k_gather(
    const int* __restrict__ off, const int* __restrict__ eidx,
    const float* __restrict__ wbuf, const float* __restrict__ Ybuf,
    float* __restrict__ wYn)
{
    __shared__ float ws[16][16];
    __shared__ float Ysh[16][16];
    int n = blockIdx.x;
    int tid = threadIdx.x;
    int m = tid >> 4, i = tid & 15;
    int beg = off[n], end = off[n + 1];
    float acc = 0.f;
    for (int c = beg; c < end; c += 16) {
        int ne = min(16, end - c);
        int j = tid >> 4, k = tid & 15;
        if (j < ne) {
            int e = eidx[c + j];
            ws[j][k] = wbuf[(size_t)e * 16 + k];
            Ysh[j][k] = Ybuf[(size_t)e * 16 + k];
        }
        __syncthreads();
        for (int j2 = 0; j2 < ne; j2++) acc += ws[j2][m] * Ysh[j2][i];
        __syncthreads();
    }
    wYn[(size_t)n * 256 + m * 16 + i] = acc * 0.25f;
}

// ---------------- vv: hs2[e][0..15] = vv, [16..31] = 0   (bf16)
__global__ __launch_bounds__(256) void k_vv(
    const float* __restrict__ abuf, const float* __restrict__ wYn0,
    const float* __restrict__ wYn1, const float* __restrict__ Ybuf,
    const int* __restrict__ snd, const float* __restrict__ Wlsh,
    __hip_bfloat16* __restrict__ hs2, int layer, int E)
{
    int idx = blockIdx.x * 256 + threadIdx.x;
    int e = idx >> 4, m = idx & 15;
    if (e >= E) return;
    int s = snd[e];
    float a = abuf[(size_t)e * 16 + m];
    const float* r0 = wYn0 + (size_t)s * 256 + m * 16;
    float vv;
    if (layer == 0) {
        vv = r0[0] * a;  // Y[e][0] == 1
    } else {
        float t = 0.f;
#pragma unroll
        for (int i = 0; i < 16; i++) t += r0[i] * Ybuf[(size_t)e * 16 + i] * Wlsh[i * 16];
        vv = wYn1[(size_t)s * 256 + m * 16] * a * t;
    }
    hs2[(size_t)e * 32 + m] = __float2bfloat16(vv);
    hs2[(size_t)e * 32 + 16 + m] = __float2bfloat16(0.f);
}

// ---------------- MFMA layer MLP: y=silu(silu([x,vv]@W1+b1)@W2+b2); x=(x+u*y)/sqrt2
__global__ __launch_bounds__(256) void k_layer_mfma(
    __hip_bfloat16* __restrict__ xb, const __hip_bfloat16* __restrict__ hs2,
    const __hip_bfloat16* __restrict__ W1s, const float* __restrict__ b1,
    const __hip_bfloat16* __restrict__ W2s, const float* __restrict__ b2,
    const float* __restrict__ ubuf)
{
    __shared__ __hip_bfloat16 ys[4][16 * 264];
    int tid = threadIdx.x;
    int w = tid >> 6, l = tid & 63;
    int lm = l & 15, lq = l >> 4;
    int erow = blockIdx.x * 64 + w * 16;
    __hip_bfloat16* Y = &ys[w][0];

    // GEMM1: [16x288] @ [288x256]  (K-tiles 0..7 from xb, 8 from hs2)
    f32x4 acc[16];
#pragma unroll
    for (int nt = 0; nt < 16; nt++) acc[nt] = (f32x4){0.f, 0.f, 0.f, 0.f};
#pragma unroll
    for (int kt = 0; kt < 9; kt++) {
        bf16x8 a;
        if (kt < 8) a = *(const bf16x8*)(xb + (size_t)(erow + lm) * H + kt * 32 + lq * 8);
        else        a = *(const bf16x8*)(hs2 + (size_t)(erow + lm) * 32 + lq * 8);
#pragma unroll
        for (int nt = 0; nt < 16; nt++) {
            bf16x8 b = *(const bf16x8*)(W1s + ((size_t)(kt * 256 + nt * 16 + lm) * 32 + lq * 8));
            acc[nt] = MFMA_B16(a, b, acc[nt]);
        }
    }
#pragma unroll
    for (int nt = 0; nt < 16; nt++) {
        int c = nt * 16 + lm;
        float bb = b1[c];
#pragma unroll
        for (int r = 0; r < 4; r++)
            Y[(lq * 4 + r) * 264 + c] = __float2bfloat16(silu(acc[nt][r] + bb));
    }
    __syncthreads();

    // GEMM2: [16x256] @ [256x256]
#pragma unroll
    for (int nt = 0; nt < 16; nt++) acc[nt] = (f32x4){0.f, 0.f, 0.f, 0.f};
#pragma unroll
    for (int kt = 0; kt < 8; kt++) {
        bf16x8 a = *(const bf16x8*)(Y + lm * 264 + kt * 32 + lq * 8);
#pragma unroll
        for (int nt = 0; nt < 16; nt++) {
            bf16x8 b = *(const bf16x8*)(W2s + ((size_t)(kt * 256 + nt * 16 + lm) * 32 + lq * 8));
            acc[nt] = MFMA_B16(a, b, acc[nt]);
        }
    }
    float uu[4];
#pragma unroll
    for (int r = 0; r < 4; r++) uu[r] = ubuf[erow + lq * 4 + r];
    const float rs2 = 0.70710678118654752f;
#pragma unroll
    for (int nt = 0; nt < 16; nt++) {
        int c = nt * 16 + lm;
        float bb = b2[c];
#pragma unroll
        for (int r = 0; r < 4; r++) {
            size_t pos = (size_t)(erow + lq * 4 + r) * H + c;
            float xo = bf2f(xb[pos]);
            float xn = (xo + uu[r] * silu(acc[nt][r] + bb)) * rs2;
            xb[pos] = __float2bfloat16(xn);
        }
    }
}

// ---------------- output: edge_out = (x @ W_out)*u ; atomic into nacc[receiver]
__global__ __launch_bounds__(256) void k_out(
    const __hip_bfloat16* __restrict__ xb, const float* __restrict__ ubuf,
    const int* __restrict__ rcv, const float* __restrict__ Wout,
    float* __restrict__ nacc)
{
    __shared__ float xs[16][H];
    __shared__ float ps[256];
    int e0 = blockIdx.x * 16;
    int tid = threadIdx.x;
    for (int idx = tid; idx < 16 * H; idx += 256)
        xs[idx >> 8][idx & 255] = bf2f(xb[(size_t)e0 * H + idx]);
    __syncthreads();
    int e = tid >> 4, lane = tid & 15;
    float p = 0.f;
#pragma unroll
    for (int j = 0; j < 16; j++) {
        int i = lane + 16 * j;
        p += xs[e][i] * Wout[i];
    }
    ps[tid] = p;
    __syncthreads();
    if (lane == 0) {
        float s = 0.f;
#pragma unroll
        for (int k = 0; k < 16; k++) s += ps[e * 16 + k];
        atomicAdd(&nacc[rcv[e0 + e]], s * ubuf[e0 + e]);
    }
}

__global__ __launch_bounds__(256) void k_final(
    const float* __restrict__ nacc, void* __restrict__ out, const int* __restrict__ flag,
    float inv, int N)
{
    int n = blockIdx.x * 256 + threadIdx.x;
    if (n >= N) return;
    float v = nacc[n] * inv;
    if (*flag) ((float*)out)[n] = v;
    else       ((__hip_bfloat16*)out)[n] = __float2bfloat16(v);
}

extern "C" void kernel_launch(void* const* d_in, const int* in_sizes, int n_in,
                              void* d_out, int out_size, void* d_ws, size_t ws_size,
                              hipStream_t stream)
{
    const int E = in_sizes[2];      // 131072
    const int N = in_sizes[0] / F;  // 8192
    (void)n_in; (void)ws_size; (void)out_size;

    char* wsb = (char*)d_ws;
    size_t off = 0;
    int* flag = (int*)wsb; off += 256;

    const int fidx[14] = {0, 1, 4, 5, 6, 7, 8, 9, 10, 11, 12, 13, 14, 15};
    float* canon[14];
    for (int k = 0; k < 14; k++) {
        canon[k] = (float*)(wsb + off);
        off += (size_t)in_sizes[fidx[k]] * 4;
        off = (off + 255) & ~(size_t)255;
    }
    const float* naC   = canon[0];
    const float* vecC  = canon[1];
    const float* We0C  = canon[2];
    const float* be0C  = canon[3];
    const float* We1C  = canon[4];
    const float* be1C  = canon[5];
    const float* Wv0C  = canon[6];
    const float* WlwC  = canon[7];
    const float* WlshC = canon[8];
    const float* Wly1C = canon[9];
    const float* bly1C = canon[10];
    const float* Wly2C = canon[11];
    const float* bly2C = canon[12];
    const float* WoutC = canon[13];

    // swizzled bf16 weights (~600 KB)
    __hip_bfloat16* We0s = (__hip_bfloat16*)(wsb + off); off += 2 * 64 * 256 * 2;  // pad
    __hip_bfloat16* We1s = (__hip_bfloat16*)(wsb + off); off += 256 * 256 * 2;
    __hip_bfloat16* Wv0s = (__hip_bfloat16*)(wsb + off); off += 256 * 16 * 2;
    __hip_bfloat16* Wlws0 = (__hip_bfloat16*)(wsb + off); off += 256 * 16 * 2;
    __hip_bfloat16* Wlws1 = (__hip_bfloat16*)(wsb + off); off += 256 * 16 * 2;
    __hip_bfloat16* W1s0 = (__hip_bfloat16*)(wsb + off); off += 288 * 256 * 2;
    __hip_bfloat16* W1s1 = (__hip_bfloat16*)(wsb + off); off += 288 * 256 * 2;
    __hip_bfloat16* W2s0 = (__hip_bfloat16*)(wsb + off); off += 256 * 256 * 2;
    __hip_bfloat16* W2s1 = (__hip_bfloat16*)(wsb + off); off += 256 * 256 * 2;
    off = (off + 255) & ~(size_t)255;

    __hip_bfloat16* xbuf = (__hip_bfloat16*)(wsb + off); off += (size_t)E * H * 2;   // 64 MB
    // fbuf (E*64 bf16 = 16 MB) dies after k_embed; recycle for wbuf (8 MB) + hs2 (8 MB)
    __hip_bfloat16* fbuf = (__hip_bfloat16*)(wsb + off);
    float*          wbuf = (float*)(wsb + off);
    __hip_bfloat16* hs2  = (__hip_bfloat16*)(wsb + off + (size_t)E * 16 * 4);
    off += (size_t)E * 64 * 2;
    float* ubuf = (float*)(wsb + off); off += (size_t)E * 4;
    float* Ybuf = (float*)(wsb + off); off += (size_t)E * 16 * 4;
    float* abuf = (float*)(wsb + off); off += (size_t)E * 16 * 4;
    float* wYn0 = (float*)(wsb + off); off += (size_t)N * H * 4;
    float* wYn1 = (float*)(wsb + off); off += (size_t)N * H * 4;
    float* nacc = (float*)(wsb + off); off += (size_t)N * 4;
    int* cnt  = (int*)(wsb + off); off += (size_t)N * 4;
    int* offb = (int*)(wsb + off); off += (size_t)(N + 1) * 4;
    int* cur  = (int*)(wsb + off); off += (size_t)N * 4;
    int* eidx = (int*)(wsb + off); off += (size_t)E * 4;

    const int* snd = (const int*)d_in[2];
    const int* rcv = (const int*)d_in[3];
    const float inv = 0.25f;
    const int nb64 = E / 64;

    // dtype sniff + canonicalization
    k_sniff<<<1, 256, 0, stream>>>(d_in[1], flag);
    for (int k = 0; k < 14; k++) {
        int n = in_sizes[fidx[k]];
        k_conv<<<(n + 255) / 256, 256, 0, stream>>>(d_in[fidx[k]], canon[k], n, flag);
    }

    // weight swizzles
    k_swz<<<(64 * 256 + 255) / 256, 256, 0, stream>>>(We0C, We0s, 40, 256, 64);
    k_swz<<<(256 * 256 + 255) / 256, 256, 0, stream>>>(We1C, We1s, 256, 256, 256);
    k_swz<<<(256 * 16 + 255) / 256, 256, 0, stream>>>(Wv0C, Wv0s, 256, 16, 256);
    k_swz<<<(256 * 16 + 255) / 256, 256, 0, stream>>>(WlwC, Wlws0, 256, 16, 256);
    k_swz<<<(256 * 16 + 255) / 256, 256, 0, stream>>>(WlwC + 256 * 16, Wlws1, 256, 16, 256);
    k_swz<<<(288 * 256 + 255) / 256, 256, 0, stream>>>(Wly1C, W1s0, 272, 256, 288);
    k_swz<<<(288 * 256 + 255) / 256, 256, 0, stream>>>(Wly1C + 272 * 256, W1s1, 272, 256, 288);
    k_swz<<<(256 * 256 + 255) / 256, 256, 0, stream>>>(Wly2C, W2s0, 256, 256, 256);
    k_swz<<<(256 * 256 + 255) / 256, 256, 0, stream>>>(Wly2C + 256 * 256, W2s1, 256, 256, 256);

    // sender CSR
    hipMemsetAsync(cnt, 0, (size_t)N * sizeof(int), stream);
    k_hist<<<(E + 255) / 256, 256, 0, stream>>>(snd, cnt, E);
    k_scan<<<1, 256, 0, stream>>>(cnt, offb, cur, N);
    k_cscatter<<<(E + 255) / 256, 256, 0, stream>>>(snd, cur, eidx, E);

    k_geom<<<(E + 255) / 256, 256, 0, stream>>>(vecC, naC, snd, rcv, ubuf, Ybuf, fbuf, E);
    k_embed_mfma<<<nb64, 256, 0, stream>>>(fbuf, We0s, be0C, We1s, be1C, Wv0s,
                                           ubuf, xbuf, abuf);

    // layer 0
    k_wcomp_mfma<<<nb64, 256, 0, stream>>>(xbuf, Wlws0, wbuf);
    k_gather<<<N, 256, 0, stream>>>(offb, eidx, wbuf, Ybuf, wYn0);
    k_vv<<<(E * 16 + 255) / 256, 256, 0, stream>>>(abuf, wYn0, wYn0, Ybuf, snd, WlshC,
                                                   hs2, 0, E);
    k_layer_mfma<<<nb64, 256, 0, stream>>>(xbuf, hs2, W1s0, bly1C, W2s0, bly2C, ubuf);
    // layer 1
    k_wcomp_mfma<<<nb64, 256, 0, stream>>>(xbuf, Wlws1, wbuf);
    k_gather<<<N, 256, 0, stream>>>(offb, eidx, wbuf, Ybuf, wYn1);
    k_vv<<<(E * 16 + 255) / 256, 256, 0, stream>>>(abuf, wYn0, wYn1, Ybuf, snd, WlshC,
                                                   hs2, 1, E);
    k_layer_mfma<<<nb64, 256, 0, stream>>>(xbuf, hs2, W1s1, bly1C + H, W2s1, bly2C + H, ubuf);

    hipMemsetAsync(nacc, 0, (size_t)N * sizeof(float), stream);
    k_out<<<E / 16, 256, 0, stream>>>(xbuf, ubuf, rcv, WoutC, nacc);
    k_final<<<(N + 255) / 256, 256, 0, stream>>>(nacc, d_out, flag, inv, N);
}

// Round 6
// 729.299 us; speedup vs baseline: 8.0190x; 1.1590x over previous
//
#include <hip/hip_runtime.h>
#include <hip/hip_bf16.h>
#include <math.h>

#define H 256
#define F 16
#define MUL 16
#define NB 8

typedef short bf16x8 __attribute__((ext_vector_type(8)));
typedef float f32x4 __attribute__((ext_vector_type(4)));
#define MFMA_B16(a, b, c) __builtin_amdgcn_mfma_f32_16x16x32_bf16(a, b, c, 0, 0, 0)

__device__ __forceinline__ float bf2f(__hip_bfloat16 x) { return __bfloat162float(x); }
__device__ __forceinline__ float silu(float x) { return x / (1.f + __expf(-x)); }

// ---------------- dtype sniffer: bf16 (flag=0) or fp32 (flag=1)?
__global__ __launch_bounds__(256) void k_sniff(const void* vec, int* flag)
{
    __shared__ int bad;
    int tid = threadIdx.x;
    if (tid == 0) bad = 0;
    __syncthreads();
    const __hip_bfloat16* hp = (const __hip_bfloat16*)vec;
    for (int i = tid; i < 1024; i += 256) {
        float f = bf2f(hp[i]);
        if (!(isfinite(f) && fabsf(f) <= 1.0f)) bad = 1;
    }
    __syncthreads();
    if (tid == 0) *flag = bad;
}

// ---------------- merged converter: 14 float inputs -> canonical fp32
struct ConvArgs {
    const void* src[14];
    float* dst[14];
    int cum[15];
};
__global__ __launch_bounds__(256) void k_conv_all(ConvArgs a, const int* __restrict__ flag)
{
    int gid = blockIdx.x * 256 + threadIdx.x;
    if (gid >= a.cum[14]) return;
    int k = 0;
    while (gid >= a.cum[k + 1]) k++;
    int i = gid - a.cum[k];
    float v = (*flag) ? ((const float*)a.src[k])[i]
                      : bf2f(((const __hip_bfloat16*)a.src[k])[i]);
    a.dst[k][i] = v;
}

// ---------------- merged weight swizzle: fp32 [K][N] -> bf16 frag-linear
// dst[(kt*N + n)*32 + kk] = W[kt*32+kk][n], zero-pad to Kpad
struct SwzArgs {
    const float* src[9];
    __hip_bfloat16* dst[9];
    int K[9], Nc[9], cum[10];
};
__global__ __launch_bounds__(256) void k_swz_all(SwzArgs a)
{
    int gid = blockIdx.x * 256 + threadIdx.x;
    if (gid >= a.cum[9]) return;
    int j = 0;
    while (gid >= a.cum[j + 1]) j++;
    int idx = gid - a.cum[j];
    int kk = idx & 31;
    int n = (idx >> 5) % a.Nc[j];
    int kt = idx / (32 * a.Nc[j]);
    int k = kt * 32 + kk;
    float v = (k < a.K[j]) ? a.src[j][(size_t)k * a.Nc[j] + n] : 0.f;
    a.dst[j][idx] = __float2bfloat16(v);
}

// ---------------- CSR build
__global__ __launch_bounds__(256) void k_hist(const int* __restrict__ snd,
                                              int* __restrict__ cnt, int E)
{
    int e = blockIdx.x * 256 + threadIdx.x;
    if (e < E) atomicAdd(&cnt[snd[e]], 1);
}

__global__ __launch_bounds__(256) void k_scan(const int* __restrict__ cnt,
                                              int* __restrict__ off,
                                              int* __restrict__ cur, int N)
{
    __shared__ int sums[256];
    int tid = threadIdx.x;
    int chunk = (N + 255) / 256;
    int base = tid * chunk;
    int s = 0;
    for (int i = 0; i < chunk; i++) { int idx = base + i; if (idx < N) s += cnt[idx]; }
    sums[tid] = s;
    __syncthreads();
    for (int d = 1; d < 256; d <<= 1) {
        int v = (tid >= d) ? sums[tid - d] : 0;
        __syncthreads();
        sums[tid] += v;
        __syncthreads();
    }
    int run = (tid == 0) ? 0 : sums[tid - 1];
    for (int i = 0; i < chunk; i++) {
        int idx = base + i;
        if (idx < N) { off[idx] = run; cur[idx] = run; run += cnt[idx]; }
    }
    if (tid == 255) off[N] = run;
}

__global__ __launch_bounds__(256) void k_cscatter(const int* __restrict__ snd,
                                                  int* __restrict__ cur,
                                                  int* __restrict__ eidx, int E)
{
    int e = blockIdx.x * 256 + threadIdx.x;
    if (e >= E) return;
    int p = atomicAdd(&cur[snd[e]], 1);
    eidx[p] = e;
}

// ---------------- geometry: u, Y(16) fp32; fbuf[E][64] bf16 = [bessel8|na_s|na_r|0]
__global__ __launch_bounds__(256) void k_geom(
    const float* __restrict__ vec, const float* __restrict__ na,
    const int* __restrict__ snd, const int* __restrict__ rcv,
    float* __restrict__ ubuf, float* __restrict__ Ybuf,
    __hip_bfloat16* __restrict__ fbuf, int E)
{
    int e = blockIdx.x * blockDim.x + threadIdx.x;
    if (e >= E) return;
    float vx = vec[3 * e + 0], vy = vec[3 * e + 1], vz = vec[3 * e + 2];
    float d = sqrtf(vx * vx + vy * vy + vz * vz);

    float d3 = d * d * d;
    float d6 = d3 * d3, d7 = d6 * d, d8 = d7 * d;
    float u = 1.f - 28.f * d6 + 48.f * d7 - 21.f * d8;
    u = (d < 1.f) ? u : 0.f;
    ubuf[e] = u;

    float invd = 1.f / d;
    const float SQ2 = 1.41421356237309515f;
    const float PI = 3.14159265358979323846f;
    __hip_bfloat16* fp = fbuf + (size_t)e * 64;
#pragma unroll
    for (int k = 1; k <= NB; k++)
        fp[k - 1] = __float2bfloat16(SQ2 * sinf((float)k * PI * d) * invd);
    int s = snd[e], r = rcv[e];
#pragma unroll
    for (int j = 0; j < 16; j++) fp[8 + j] = __float2bfloat16(na[(size_t)s * F + j]);
#pragma unroll
    for (int j = 0; j < 16; j++) fp[24 + j] = __float2bfloat16(na[(size_t)r * F + j]);
#pragma unroll
    for (int j = 40; j < 64; j++) fp[j] = __float2bfloat16(0.f);

    float x = vx * invd, y = vy * invd, z = vz * invd;
    const float s3 = 1.7320508075688772f;
    const float s5 = 2.2360679774997896f;
    const float s15 = 3.8729833462074170f;
    const float s7 = 2.6457513110645907f;
    const float c33 = 2.0916500663351889f;
    const float c32 = 10.246950765959598f;
    const float c31 = 1.6201851746019651f;
    float* Yp = Ybuf + (size_t)e * 16;
    Yp[0] = 1.f;
    Yp[1] = s3 * x;  Yp[2] = s3 * y;  Yp[3] = s3 * z;
    Yp[4] = s15 * x * y;  Yp[5] = s15 * y * z;
    Yp[6] = 0.5f * s5 * (3.f * z * z - 1.f);
    Yp[7] = s15 * x * z;
    Yp[8] = 0.5f * s15 * (x * x - y * y);
    Yp[9] = c33 * y * (3.f * x * x - y * y);
    Yp[10] = c32 * x * y * z;
    Yp[11] = c31 * y * (5.f * z * z - 1.f);
    Yp[12] = 0.5f * s7 * (5.f * z * z * z - 3.f * z);
    Yp[13] = c31 * x * (5.f * z * z - 1.f);
    Yp[14] = 0.5f * c32 * z * (x * x - y * y);
    Yp[15] = c33 * x * (x * x - 3.f * y * y);
}

// ---------------- MFMA embed (M=32/wave, 128 edges/block) + fused a & w0
__global__ __launch_bounds__(256, 2) void k_embed_mfma(
    const __hip_bfloat16* __restrict__ fbuf,
    const __hip_bfloat16* __restrict__ We0s, const float* __restrict__ be0,
    const __hip_bfloat16* __restrict__ We1s, const float* __restrict__ be1,
    const __hip_bfloat16* __restrict__ Wv0s, const __hip_bfloat16* __restrict__ Wlws0,
    const float* __restrict__ ubuf,
    __hip_bfloat16* __restrict__ xb, float* __restrict__ abuf,
    float* __restrict__ wbuf)
{
    __shared__ __align__(16) __hip_bfloat16 ys[4][32 * 264];
    int tid = threadIdx.x;
    int w = tid >> 6, l = tid & 63;
    int lm = l & 15, lq = l >> 4;
    int erow = blockIdx.x * 128 + w * 32;
    __hip_bfloat16* Y = &ys[w][0];

    // GEMM1: [32x64] @ [64x256]
    f32x4 acc0[16], acc1[16];
#pragma unroll
    for (int nt = 0; nt < 16; nt++) {
        acc0[nt] = (f32x4){0.f, 0.f, 0.f, 0.f};
        acc1[nt] = (f32x4){0.f, 0.f, 0.f, 0.f};
    }
#pragma unroll
    for (int kt = 0; kt < 2; kt++) {
        bf16x8 a0 = *(const bf16x8*)(fbuf + (size_t)(erow + lm) * 64 + kt * 32 + lq * 8);
        bf16x8 a1 = *(const bf16x8*)(fbuf + (size_t)(erow + 16 + lm) * 64 + kt * 32 + lq * 8);
#pragma unroll
        for (int nt = 0; nt < 16; nt++) {
            bf16x8 b = *(const bf16x8*)(We0s + ((size_t)(kt * 256 + nt * 16 + lm) * 32 + lq * 8));
            acc0[nt] = MFMA_B16(a0, b, acc0[nt]);
            acc1[nt] = MFMA_B16(a1, b, acc1[nt]);
        }
    }
#pragma unroll
    for (int nt = 0; nt < 16; nt++) {
        int c = nt * 16 + lm;
        float bb = be0[c];
#pragma unroll
        for (int r = 0; r < 4; r++) {
            Y[(lq * 4 + r) * 264 + c] = __float2bfloat16(silu(acc0[nt][r] + bb));
            Y[(16 + lq * 4 + r) * 264 + c] = __float2bfloat16(silu(acc1[nt][r] + bb));
        }
    }
    __syncthreads();

    // GEMM2: [32x256] @ [256x256]
#pragma unroll
    for (int nt = 0; nt < 16; nt++) {
        acc0[nt] = (f32x4){0.f, 0.f, 0.f, 0.f};
        acc1[nt] = (f32x4){0.f, 0.f, 0.f, 0.f};
    }
#pragma unroll
    for (int kt = 0; kt < 8; kt++) {
        bf16x8 a0 = *(const bf16x8*)(Y + lm * 264 + kt * 32 + lq * 8);
        bf16x8 a1 = *(const bf16x8*)(Y + (16 + lm) * 264 + kt * 32 + lq * 8);
#pragma unroll
        for (int nt = 0; nt < 16; nt++) {
            bf16x8 b = *(const bf16x8*)(We1s + ((size_t)(kt * 256 + nt * 16 + lm) * 32 + lq * 8));
            acc0[nt] = MFMA_B16(a0, b, acc0[nt]);
            acc1[nt] = MFMA_B16(a1, b, acc1[nt]);
        }
    }
    __syncthreads();
    float u0[4], u1[4];
#pragma unroll
    for (int r = 0; r < 4; r++) {
        u0[r] = ubuf[erow + lq * 4 + r];
        u1[r] = ubuf[erow + 16 + lq * 4 + r];
    }
#pragma unroll
    for (int nt = 0; nt < 16; nt++) {
        int c = nt * 16 + lm;
        float bb = be1[c];
#pragma unroll
        for (int r = 0; r < 4; r++) {
            float v0 = silu(acc0[nt][r] + bb) * u0[r];
            float v1 = silu(acc1[nt][r] + bb) * u1[r];
            __hip_bfloat16 h0 = __float2bfloat16(v0);
            __hip_bfloat16 h1 = __float2bfloat16(v1);
            xb[(size_t)(erow + lq * 4 + r) * H + c] = h0;
            xb[(size_t)(erow + 16 + lq * 4 + r) * H + c] = h1;
            Y[(lq * 4 + r) * 264 + c] = h0;
            Y[(16 + lq * 4 + r) * 264 + c] = h1;
        }
    }
    __syncthreads();

    // GEMM3 (a = x@Wv0) + wcomp0 (w = x@Wlw0), both [32x256]@[256x16]
    f32x4 av0 = (f32x4){0.f, 0.f, 0.f, 0.f}, av1 = (f32x4){0.f, 0.f, 0.f, 0.f};
    f32x4 aw0 = (f32x4){0.f, 0.f, 0.f, 0.f}, aw1 = (f32x4){0.f, 0.f, 0.f, 0.f};
#pragma unroll
    for (int kt = 0; kt < 8; kt++) {
        bf16x8 a0 = *(const bf16x8*)(Y + lm * 264 + kt * 32 + lq * 8);
        bf16x8 a1 = *(const bf16x8*)(Y + (16 + lm) * 264 + kt * 32 + lq * 8);
        bf16x8 bv = *(const bf16x8*)(Wv0s + ((size_t)(kt * 16 + lm) * 32 + lq * 8));
        bf16x8 bw = *(const bf16x8*)(Wlws0 + ((size_t)(kt * 16 + lm) * 32 + lq * 8));
        av0 = MFMA_B16(a0, bv, av0);
        av1 = MFMA_B16(a1, bv, av1);
        aw0 = MFMA_B16(a0, bw, aw0);
        aw1 = MFMA_B16(a1, bw, aw1);
    }
#pragma unroll
    for (int r = 0; r < 4; r++) {
        abuf[(size_t)(erow + lq * 4 + r) * 16 + lm] = av0[r];
        abuf[(size_t)(erow + 16 + lq * 4 + r) * 16 + lm] = av1[r];
        wbuf[(size_t)(erow + lq * 4 + r) * 16 + lm] = aw0[r];
        wbuf[(size_t)(erow + 16 + lq * 4 + r) * 16 + lm] = aw1[r];
    }
}

// ---------------- CSR gather: wYn[n,m,i] = inv * sum_e w[e,m]*Y[e,i]
__global__ __launch_bounds__(256) void k_gather(
    const int* __restrict__ off, const int* __restrict__ eidx,
    const float* __restrict__ wbuf, const float* __restrict__ Ybuf,
    float* __restrict__ wYn)
{
    __shared__ float ws[16][16];
    __shared__ float Ysh[16][16];
    int n = blockIdx.x;
    int tid = threadIdx.x;
    int m = tid >> 4, i = tid & 15;
    int beg = off[n], end = off[n + 1];
    float acc = 0.f;
    for (int c = beg; c < end; c += 16) {
        int ne = min(16, end - c);
        int j = tid >> 4, k = tid & 15;
        if (j < ne) {
            int e = eidx[c + j];
            ws[j][k] = wbuf[(size_t)e * 16 + k];
            Ysh[j][k] = Ybuf[(size_t)e * 16 + k];
        }
        __syncthreads();
        for (int j2 = 0; j2 < ne; j2++) acc += ws[j2][m] * Ysh[j2][i];
        __syncthreads();
    }
    wYn[(size_t)n * 256 + m * 16 + i] = acc * 0.25f;
}

// ---------------- MFMA layer (M=32/wave): vv prologue + MLP + residual + w_next
__global__ __launch_bounds__(256, 2) void k_layer_mfma(
    __hip_bfloat16* __restrict__ xb, const float* __restrict__ abuf,
    const float* __restrict__ Ybuf, const float* __restrict__ ubuf,
    const int* __restrict__ snd,
    const float* __restrict__ wYn0, const float* __restrict__ wYn1,
    const float* __restrict__ Wlsh,
    const __hip_bfloat16* __restrict__ W1s, const float* __restrict__ b1,
    const __hip_bfloat16* __restrict__ W2s, const float* __restrict__ b2,
    const __hip_bfloat16* __restrict__ Wlwn, float* __restrict__ wbufn,
    int layer)
{
    __shared__ __align__(16) __hip_bfloat16 ys[4][32 * 264];
    __shared__ __align__(16) __hip_bfloat16 vvs[128][40];
    int tid = threadIdx.x;
    int w = tid >> 6, l = tid & 63;
    int lm = l & 15, lq = l >> 4;
    int e0 = blockIdx.x * 128;
    int erow = e0 + w * 32;
    __hip_bfloat16* Y = &ys[w][0];

    // prologue: vv for the block's 128 edges -> vvs[:, 0..15], zeros in 16..31
    {
        int el = tid & 127;
        int mh = (tid >> 7) * 8;
        int ge = e0 + el;
        int s = snd[ge];
        const float* w0 = wYn0 + (size_t)s * 256;
#pragma unroll
        for (int mi = 0; mi < 8; mi++) {
            int m = mh + mi;
            float a = abuf[(size_t)ge * 16 + m];
            float vv;
            if (layer == 0) {
                vv = w0[m * 16] * a;  // Y[e][0] == 1
            } else {
                float t = 0.f;
#pragma unroll
                for (int i = 0; i < 16; i++)
                    t += w0[m * 16 + i] * Ybuf[(size_t)ge * 16 + i] * Wlsh[i * 16];
                vv = wYn1[(size_t)s * 256 + m * 16] * a * t;
            }
            vvs[el][m] = __float2bfloat16(vv);
            vvs[el][16 + m] = __float2bfloat16(0.f);
        }
    }
    __syncthreads();

    // GEMM1: [32x288] @ [288x256]  (kt 0..7 from xb, kt 8 from vvs)
    f32x4 acc0[16], acc1[16];
#pragma unroll
    for (int nt = 0; nt < 16; nt++) {
        acc0[nt] = (f32x4){0.f, 0.f, 0.f, 0.f};
        acc1[nt] = (f32x4){0.f, 0.f, 0.f, 0.f};
    }
#pragma unroll
    for (int kt = 0; kt < 9; kt++) {
        bf16x8 a0, a1;
        if (kt < 8) {
            a0 = *(const bf16x8*)(xb + (size_t)(erow + lm) * H + kt * 32 + lq * 8);
            a1 = *(const bf16x8*)(xb + (size_t)(erow + 16 + lm) * H + kt * 32 + lq * 8);
        } else {
            a0 = *(const bf16x8*)(&vvs[w * 32 + lm][lq * 8]);
            a1 = *(const bf16x8*)(&vvs[w * 32 + 16 + lm][lq * 8]);
        }
#pragma unroll
        for (int nt = 0; nt < 16; nt++) {
            bf16x8 b = *(const bf16x8*)(W1s + ((size_t)(kt * 256 + nt * 16 + lm) * 32 + lq * 8));
            acc0[nt] = MFMA_B16(a0, b, acc0[nt]);
            acc1[nt] = MFMA_B16(a1, b, acc1[nt]);
        }
    }
#pragma unroll
    for (int nt = 0; nt < 16; nt++) {
        int c = nt * 16 + lm;
        float bb = b1[c];
#pragma unroll
        for (int r = 0; r < 4; r++) {
            Y[(lq * 4 + r) * 264 + c] = __float2bfloat16(silu(acc0[nt][r] + bb));
            Y[(16 + lq * 4 + r) * 264 + c] = __float2bfloat16(silu(acc1[nt][r] + bb));
        }
    }
    __syncthreads();

    // GEMM2: [32x256] @ [256x256]
#pragma unroll
    for (int nt = 0; nt < 16; nt++) {
        acc0[nt] = (f32x4){0.f, 0.f, 0.f, 0.f};
        acc1[nt] = (f32x4){0.f, 0.f, 0.f, 0.f};
    }
#pragma unroll
    for (int kt = 0; kt < 8; kt++) {
        bf16x8 a0 = *(const bf16x8*)(Y + lm * 264 + kt * 32 + lq * 8);
        bf16x8 a1 = *(const bf16x8*)(Y + (16 + lm) * 264 + kt * 32 + lq * 8);
#pragma unroll
        for (int nt = 0; nt < 16; nt++) {
            bf16x8 b = *(const bf16x8*)(W2s + ((size_t)(kt * 256 + nt * 16 + lm) * 32 + lq * 8));
            acc0[nt] = MFMA_B16(a0, b, acc0[nt]);
            acc1[nt] = MFMA_B16(a1, b, acc1[nt]);
        }
    }
    __syncthreads();
    float u0[4], u1[4];
#pragma unroll
    for (int r = 0; r < 4; r++) {
        u0[r] = ubuf[erow + lq * 4 + r];
        u1[r] = ubuf[erow + 16 + lq * 4 + r];
    }
    const float rs2 = 0.70710678118654752f;
#pragma unroll
    for (int nt = 0; nt < 16; nt++) {
        int c = nt * 16 + lm;
        float bb = b2[c];
#pragma unroll
        for (int r = 0; r < 4; r++) {
            size_t p0 = (size_t)(erow + lq * 4 + r) * H + c;
            size_t p1 = (size_t)(erow + 16 + lq * 4 + r) * H + c;
            float xn0 = (bf2f(xb[p0]) + u0[r] * silu(acc0[nt][r] + bb)) * rs2;
            float xn1 = (bf2f(xb[p1]) + u1[r] * silu(acc1[nt][r] + bb)) * rs2;
            __hip_bfloat16 h0 = __float2bfloat16(xn0);
            __hip_bfloat16 h1 = __float2bfloat16(xn1);
            xb[p0] = h0;
            xb[p1] = h1;
            if (Wlwn) {
                Y[(lq * 4 + r) * 264 + c] = h0;
                Y[(16 + lq * 4 + r) * 264 + c] = h1;
            }
        }
    }
    if (Wlwn) {
        // wcomp for next layer: w = x_new @ Wlwn  [32x256]@[256x16]
        f32x4 c0 = (f32x4){0.f, 0.f, 0.f, 0.f}, c1 = (f32x4){0.f, 0.f, 0.f, 0.f};
#pragma unroll
        for (int kt = 0; kt < 8; kt++) {
            bf16x8 a0 = *(const bf16x8*)(Y + lm * 264 + kt * 32 + lq * 8);
            bf16x8 a1 = *(const bf16x8*)(Y + (16 + lm) * 264 + kt * 32 + lq * 8);
            bf16x8 b = *(const bf16x8*)(Wlwn + ((size_t)(kt * 16 + lm) * 32 + lq * 8));
            c0 = MFMA_B16(a0, b, c0);
            c1 = MFMA_B16(a1, b, c1);
        }
#pragma unroll
        for (int r = 0; r < 4; r++) {
            wbufn[(size_t)(erow + lq * 4 + r) * 16 + lm] = c0[r];
            wbufn[(size_t)(erow + 16 + lq * 4 + r) * 16 + lm] = c1[r];
        }
    }
}

// ---------------- output: edge_out = (x @ W_out)*u ; atomic into nacc[receiver]
__global__ __launch_bounds__(256) void k_out(
    const __hip_bfloat16* __restrict__ xb, const float* __restrict__ ubuf,
    const int* __restrict__ rcv, const float* __restrict__ Wout,
    float* __restrict__ nacc)
{
    __shared__ float xs[16][H];
    __shared__ float ps[256];
    int e0 = blockIdx.x * 16;
    int tid = threadIdx.x;
    for (int idx = tid; idx < 16 * H; idx += 256)
        xs[idx >> 8][idx & 255] = bf2f(xb[(size_t)e0 * H + idx]);
    __syncthreads();
    int e = tid >> 4, lane = tid & 15;
    float p = 0.f;
#pragma unroll
    for (int j = 0; j < 16; j++) {
        int i = lane + 16 * j;
        p += xs[e][i] * Wout[i];
    }
    ps[tid] = p;
    __syncthreads();
    if (lane == 0) {
        float s = 0.f;
#pragma unroll
        for (int k = 0; k < 16; k++) s += ps[e * 16 + k];
        atomicAdd(&nacc[rcv[e0 + e]], s * ubuf[e0 + e]);
    }
}

__global__ __launch_bounds__(256) void k_final(
    const float* __restrict__ nacc, void* __restrict__ out, const int* __restrict__ flag,
    float inv, int N)
{
    int n = blockIdx.x * 256 + threadIdx.x;
    if (n >= N) return;
    float v = nacc[n] * inv;
    if (*flag) ((float*)out)[n] = v;
    else       ((__hip_bfloat16*)out)[n] = __float2bfloat16(v);
}

extern "C" void kernel_launch(void* const* d_in, const int* in_sizes, int n_in,
                              void* d_out, int out_size, void* d_ws, size_t ws_size,
                              hipStream_t stream)
{
    const int E = in_sizes[2];      // 131072
    const int N = in_sizes[0] / F;  // 8192
    (void)n_in; (void)ws_size; (void)out_size;

    char* wsb = (char*)d_ws;
    size_t off = 0;
    int* flag = (int*)wsb; off += 256;

    const int fidx[14] = {0, 1, 4, 5, 6, 7, 8, 9, 10, 11, 12, 13, 14, 15};
    float* canon[14];
    for (int k = 0; k < 14; k++) {
        canon[k] = (float*)(wsb + off);
        off += (size_t)in_sizes[fidx[k]] * 4;
        off = (off + 255) & ~(size_t)255;
    }
    const float* naC   = canon[0];
    const float* vecC  = canon[1];
    const float* We0C  = canon[2];
    const float* be0C  = canon[3];
    const float* We1C  = canon[4];
    const float* be1C  = canon[5];
    const float* Wv0C  = canon[6];
    const float* WlwC  = canon[7];
    const float* WlshC = canon[8];
    const float* Wly1C = canon[9];
    const float* bly1C = canon[10];
    const float* Wly2C = canon[11];
    const float* bly2C = canon[12];
    const float* WoutC = canon[13];

    // swizzled bf16 weights
    __hip_bfloat16* We0s  = (__hip_bfloat16*)(wsb + off); off += 64 * 256 * 2;
    __hip_bfloat16* We1s  = (__hip_bfloat16*)(wsb + off); off += 256 * 256 * 2;
    __hip_bfloat16* Wv0s  = (__hip_bfloat16*)(wsb + off); off += 256 * 16 * 2;
    __hip_bfloat16* Wlws0 = (__hip_bfloat16*)(wsb + off); off += 256 * 16 * 2;
    __hip_bfloat16* Wlws1 = (__hip_bfloat16*)(wsb + off); off += 256 * 16 * 2;
    __hip_bfloat16* W1s0  = (__hip_bfloat16*)(wsb + off); off += 288 * 256 * 2;
    __hip_bfloat16* W1s1  = (__hip_bfloat16*)(wsb + off); off += 288 * 256 * 2;
    __hip_bfloat16* W2s0  = (__hip_bfloat16*)(wsb + off); off += 256 * 256 * 2;
    __hip_bfloat16* W2s1  = (__hip_bfloat16*)(wsb + off); off += 256 * 256 * 2;
    off = (off + 255) & ~(size_t)255;

    __hip_bfloat16* xbuf = (__hip_bfloat16*)(wsb + off); off += (size_t)E * H * 2;
    // fbuf (E*64 bf16 = 16 MB) dies after k_embed; wYn0/wYn1 (8+8 MB) first
    // written by k_gather afterwards -> alias the same 16 MB region.
    __hip_bfloat16* fbuf = (__hip_bfloat16*)(wsb + off);
    float* wYn0 = (float*)(wsb + off);
    float* wYn1 = (float*)(wsb + off + (size_t)N * H * 4);
    off += (size_t)E * 64 * 2;
    float* ubuf = (float*)(wsb + off); off += (size_t)E * 4;
    float* Ybuf = (float*)(wsb + off); off += (size_t)E * 16 * 4;
    float* abuf = (float*)(wsb + off); off += (size_t)E * 16 * 4;
    float* wbuf = (float*)(wsb + off); off += (size_t)E * 16 * 4;
    float* nacc = (float*)(wsb + off); off += (size_t)N * 4;
    int* cnt  = (int*)(wsb + off); off += (size_t)N * 4;
    int* offb = (int*)(wsb + off); off += (size_t)(N + 1) * 4;
    int* cur  = (int*)(wsb + off); off += (size_t)N * 4;
    int* eidx = (int*)(wsb + off); off += (size_t)E * 4;

    const int* snd = (const int*)d_in[2];
    const int* rcv = (const int*)d_in[3];
    const float inv = 0.25f;
    const int nb128 = E / 128;

    // dtype sniff + merged canonicalization
    k_sniff<<<1, 256, 0, stream>>>(d_in[1], flag);
    {
        ConvArgs ca;
        int c = 0;
        for (int k = 0; k < 14; k++) {
            ca.src[k] = d_in[fidx[k]];
            ca.dst[k] = canon[k];
            ca.cum[k] = c;
            c += in_sizes[fidx[k]];
        }
        ca.cum[14] = c;
        k_conv_all<<<(c + 255) / 256, 256, 0, stream>>>(ca, flag);
    }

    // merged weight swizzles
    {
        SwzArgs sa;
        const float* srcs[9] = {We0C, We1C, Wv0C, WlwC, WlwC + 256 * 16,
                                Wly1C, Wly1C + 272 * 256, Wly2C, Wly2C + 256 * 256};
        __hip_bfloat16* dsts[9] = {We0s, We1s, Wv0s, Wlws0, Wlws1, W1s0, W1s1, W2s0, W2s1};
        int Ks[9]    = {40, 256, 256, 256, 256, 272, 272, 256, 256};
        int Ncs[9]   = {256, 256, 16, 16, 16, 256, 256, 256, 256};
        int Kpads[9] = {64, 256, 256, 256, 256, 288, 288, 256, 256};
        int c = 0;
        for (int j = 0; j < 9; j++) {
            sa.src[j] = srcs[j]; sa.dst[j] = dsts[j];
            sa.K[j] = Ks[j]; sa.Nc[j] = Ncs[j];
            sa.cum[j] = c;
            c += (Kpads[j] >> 5) * Ncs[j] * 32;
        }
        sa.cum[9] = c;
        k_swz_all<<<(c + 255) / 256, 256, 0, stream>>>(sa);
    }

    // sender CSR
    hipMemsetAsync(cnt, 0, (size_t)N * sizeof(int), stream);
    k_hist<<<(E + 255) / 256, 256, 0, stream>>>(snd, cnt, E);
    k_scan<<<1, 256, 0, stream>>>(cnt, offb, cur, N);
    k_cscatter<<<(E + 255) / 256, 256, 0, stream>>>(snd, cur, eidx, E);

    k_geom<<<(E + 255) / 256, 256, 0, stream>>>(vecC, naC, snd, rcv, ubuf, Ybuf, fbuf, E);
    k_embed_mfma<<<nb128, 256, 0, stream>>>(fbuf, We0s, be0C, We1s, be1C, Wv0s, Wlws0,
                                            ubuf, xbuf, abuf, wbuf);

    // layer 0 (emits w for layer 1 into wbuf)
    k_gather<<<N, 256, 0, stream>>>(offb, eidx, wbuf, Ybuf, wYn0);
    k_layer_mfma<<<nb128, 256, 0, stream>>>(xbuf, abuf, Ybuf, ubuf, snd, wYn0, wYn0,
                                            WlshC, W1s0, bly1C, W2s0, bly2C,
                                            Wlws1, wbuf, 0);
    // layer 1
    k_gather<<<N, 256, 0, stream>>>(offb, eidx, wbuf, Ybuf, wYn1);
    k_layer_mfma<<<nb128, 256, 0, stream>>>(xbuf, abuf, Ybuf, ubuf, snd, wYn0, wYn1,
                                            WlshC, W1s1, bly1C + H, W2s1, bly2C + H,
                                            (const __hip_bfloat16*)nullptr, (float*)nullptr, 1);

    hipMemsetAsync(nacc, 0, (size_t)N * sizeof(float), stream);
    k_out<<<E / 16, 256, 0, stream>>>(xbuf, ubuf, rcv, WoutC, nacc);
    k_final<<<(N + 255) / 256, 256, 0, stream>>>(nacc, d_out, flag, inv, N);
}